// Round 2
// baseline (4674.062 us; speedup 1.0000x reference)
//
#include <hip/hip_runtime.h>
#include <cstdint>
#include <cstddef>

#define BB 512
#define TT 1024
#define FF 128
#define HH 128
#define AA 16
#define TB 32   // t-rows per gemm block

// ---------------- Phase 1: cur1[b][t][h] = x[b,t,:] . W1[h,:] + b1[h] ----------------
// Bitwise-identical strand order to round-1's in-loop dot:
// 4 strands over float4 components, combined ((s0+s1)+(s2+s3)) + b1h.
__global__ __launch_bounds__(128, 1) void gemm_cur1(
    const float* __restrict__ X,    // (B,T,F)
    const float* __restrict__ W1,   // (H,F)
    const float* __restrict__ b1,   // (H)
    float* __restrict__ cur1,       // (B,Tc,H) chunk buffer
    int t0, int Tc)
{
    const int tid = threadIdx.x;
    const int b = blockIdx.y;
    const int tloc = blockIdx.x * TB;          // t offset within chunk

    // W1 row tid pinned in VGPRs (empty asm blocks rematerialization).
    float4 w1q[32];
    {
        const float4* w1p = (const float4*)(W1 + tid * FF);
        #pragma unroll
        for (int q = 0; q < 32; ++q) {
            float4 v = w1p[q];
            asm volatile("" : "+v"(v.x), "+v"(v.y), "+v"(v.z), "+v"(v.w));
            w1q[q] = v;
        }
    }
    const float b1h = b1[tid];

    const float* xrow = X + ((size_t)b * TT + (t0 + tloc)) * FF;
    float* crow = cur1 + ((size_t)b * Tc + tloc) * HH;

    for (int t = 0; t < TB; ++t) {
        const float4* x4 = (const float4*)xrow;
        float s0 = 0.f, s1 = 0.f, s2 = 0.f, s3 = 0.f;
        #pragma unroll
        for (int q = 0; q < 32; ++q) {
            float4 xv = x4[q];
            s0 = fmaf(xv.x, w1q[q].x, s0);
            s1 = fmaf(xv.y, w1q[q].y, s1);
            s2 = fmaf(xv.z, w1q[q].z, s2);
            s3 = fmaf(xv.w, w1q[q].w, s3);
        }
        crow[tid] = ((s0 + s1) + (s2 + s3)) + b1h;
        xrow += FF;
        crow += HH;
    }
}

// ---------------- Phase 2: the scan. One wave per batch element. ----------------
// lane owns h0=lane, h1=lane+64 (and j0/j1 likewise). Spike exchange via two
// __ballot()s -> SGPR masks. cur2 dense: SALU bit->float + v_fmac on
// VGPR-resident W2 rows. Zero barriers, zero LDS (shuffles only for `out`,
// which is off the recurrence critical path).
__global__ __launch_bounds__(64, 1) void scan_lif(
    const float* __restrict__ cur1,    // (B,Tc,H)
    const float* __restrict__ mem_in,  // (B,2,H): b*256 + sel*128 + h
    float* __restrict__ mem_out,       // same layout
    const float* __restrict__ beta1,
    const float* __restrict__ W2,      // (H,H)
    const float* __restrict__ b2,
    const float* __restrict__ beta2,
    const float* __restrict__ W3,      // (A,H)
    const float* __restrict__ b3,
    float* __restrict__ out,           // (B,T,A)
    int t0, int Tc)
{
    const int lane = threadIdx.x;
    const int b = blockIdx.x;
    const int a = lane & 15;
    const int gp = lane >> 4;

    // W2 rows j0=lane and j1=lane+64, pinned in VGPRs (256 regs).
    float w2a[128], w2b[128];
    {
        const float4* p0 = (const float4*)(W2 + lane * HH);
        const float4* p1 = (const float4*)(W2 + (lane + 64) * HH);
        #pragma unroll
        for (int q = 0; q < 32; ++q) {
            float4 v = p0[q];
            asm volatile("" : "+v"(v.x), "+v"(v.y), "+v"(v.z), "+v"(v.w));
            w2a[4*q+0] = v.x; w2a[4*q+1] = v.y; w2a[4*q+2] = v.z; w2a[4*q+3] = v.w;
            float4 u = p1[q];
            asm volatile("" : "+v"(u.x), "+v"(u.y), "+v"(u.z), "+v"(u.w));
            w2b[4*q+0] = u.x; w2b[4*q+1] = u.y; w2b[4*q+2] = u.z; w2b[4*q+3] = u.w;
        }
    }
    // W3 slice: a = lane&15, j in [32*gp, 32*gp+32) -> 32 regs.
    float w3r[32];
    {
        const float4* p3 = (const float4*)(W3 + a * HH + gp * 32);
        #pragma unroll
        for (int q = 0; q < 8; ++q) {
            float4 v = p3[q];
            asm volatile("" : "+v"(v.x), "+v"(v.y), "+v"(v.z), "+v"(v.w));
            w3r[4*q+0] = v.x; w3r[4*q+1] = v.y; w3r[4*q+2] = v.z; w3r[4*q+3] = v.w;
        }
    }

    float mem10 = mem_in[b * 256 + lane];
    float mem11 = mem_in[b * 256 + lane + 64];
    float mem20 = mem_in[b * 256 + 128 + lane];
    float mem21 = mem_in[b * 256 + 128 + lane + 64];

    const float bt10 = fminf(fmaxf(beta1[lane], 0.f), 1.f);
    const float bt11 = fminf(fmaxf(beta1[lane + 64], 0.f), 1.f);
    const float bt20 = fminf(fmaxf(beta2[lane], 0.f), 1.f);
    const float bt21 = fminf(fmaxf(beta2[lane + 64], 0.f), 1.f);
    const float b2j0 = b2[lane];
    const float b2j1 = b2[lane + 64];
    const float b3a = b3[a];

    const float* cb = cur1 + (size_t)b * Tc * HH;
    float* orow = out + (size_t)b * TT * AA;

    // Prefetch t=0.
    float c10 = cb[lane];
    float c11 = cb[lane + 64];

    for (int t = 0; t < Tc; ++t) {
        // Prefetch next step's cur1 (consumed at loop end -> latency hidden).
        const int tn = (t + 1 < Tc) ? (t + 1) : t;
        const float n0 = cb[(size_t)tn * HH + lane];
        const float n1 = cb[(size_t)tn * HH + lane + 64];

        // ---- LIF1 (reset uses OLD mem) ----
        const float r10 = (mem10 > 1.0f) ? 1.0f : 0.0f;
        mem10 = bt10 * mem10 + c10 - r10;
        const int sp10 = (mem10 - 1.0f) > 0.0f;
        const float r11 = (mem11 > 1.0f) ? 1.0f : 0.0f;
        mem11 = bt11 * mem11 + c11 - r11;
        const int sp11 = (mem11 - 1.0f) > 0.0f;

        const unsigned long long m1lo = __ballot(sp10);  // bits = h 0..63
        const unsigned long long m1hi = __ballot(sp11);  // bits = h 64..127
        const unsigned mA = __builtin_amdgcn_readfirstlane((unsigned)m1lo);
        const unsigned mB = __builtin_amdgcn_readfirstlane((unsigned)(m1lo >> 32));
        const unsigned mC = __builtin_amdgcn_readfirstlane((unsigned)m1hi);
        const unsigned mD = __builtin_amdgcn_readfirstlane((unsigned)(m1hi >> 32));

        // ---- cur2: dense, scalar bit floats; order matches round 1
        // (c2a: h 0-31 then 64-95; c2b: 32-63 then 96-127; +0.0 is neutral) ----
        float c2a0 = b2j0, c2b0 = 0.f;
        float c2a1 = b2j1, c2b1 = 0.f;
        #pragma unroll
        for (int h = 0; h < 32; ++h) {
            const float bit = ((mA >> h) & 1u) ? 1.0f : 0.0f;
            c2a0 = fmaf(bit, w2a[h], c2a0);
            c2a1 = fmaf(bit, w2b[h], c2a1);
        }
        #pragma unroll
        for (int h = 0; h < 32; ++h) {
            const float bit = ((mB >> h) & 1u) ? 1.0f : 0.0f;
            c2b0 = fmaf(bit, w2a[32 + h], c2b0);
            c2b1 = fmaf(bit, w2b[32 + h], c2b1);
        }
        #pragma unroll
        for (int h = 0; h < 32; ++h) {
            const float bit = ((mC >> h) & 1u) ? 1.0f : 0.0f;
            c2a0 = fmaf(bit, w2a[64 + h], c2a0);
            c2a1 = fmaf(bit, w2b[64 + h], c2a1);
        }
        #pragma unroll
        for (int h = 0; h < 32; ++h) {
            const float bit = ((mD >> h) & 1u) ? 1.0f : 0.0f;
            c2b0 = fmaf(bit, w2a[96 + h], c2b0);
            c2b1 = fmaf(bit, w2b[96 + h], c2b1);
        }
        const float cur20 = c2a0 + c2b0;
        const float cur21 = c2a1 + c2b1;

        // ---- LIF2 ----
        const float r20 = (mem20 > 1.0f) ? 1.0f : 0.0f;
        mem20 = bt20 * mem20 + cur20 - r20;
        const int sp20 = (mem20 - 1.0f) > 0.0f;
        const float r21 = (mem21 > 1.0f) ? 1.0f : 0.0f;
        mem21 = bt21 * mem21 + cur21 - r21;
        const int sp21 = (mem21 - 1.0f) > 0.0f;

        const unsigned long long m2lo = __ballot(sp20);
        const unsigned long long m2hi = __ballot(sp21);
        const unsigned nA = __builtin_amdgcn_readfirstlane((unsigned)m2lo);
        const unsigned nB = __builtin_amdgcn_readfirstlane((unsigned)(m2lo >> 32));
        const unsigned nC = __builtin_amdgcn_readfirstlane((unsigned)m2hi);
        const unsigned nD = __builtin_amdgcn_readfirstlane((unsigned)(m2hi >> 32));

        // ---- out[a] = b3[a] + sum_j spk2[j]*W3[a,j] (not fed back; off path) ----
        const unsigned mw = (gp == 0) ? nA : (gp == 1) ? nB : (gp == 2) ? nC : nD;
        float pa = 0.f, pb = 0.f;
        #pragma unroll
        for (int k = 0; k < 16; ++k) {
            pa = fmaf((float)((mw >> k) & 1u), w3r[k], pa);
            pb = fmaf((float)((mw >> (k + 16)) & 1u), w3r[k + 16], pb);
        }
        float p = pa + pb;
        p += __shfl_down(p, 16);
        p += __shfl_down(p, 32);
        if (gp == 0) orow[(size_t)(t0 + t) * AA + a] = b3a + p;

        c10 = n0;
        c11 = n1;
    }

    mem_out[b * 256 + lane] = mem10;
    mem_out[b * 256 + lane + 64] = mem11;
    mem_out[b * 256 + 128 + lane] = mem20;
    mem_out[b * 256 + 128 + lane + 64] = mem21;
}

extern "C" void kernel_launch(void* const* d_in, const int* in_sizes, int n_in,
                              void* d_out, int out_size, void* d_ws, size_t ws_size,
                              hipStream_t stream) {
    const float* X     = (const float*)d_in[0];
    const float* hid   = (const float*)d_in[1];
    const float* W1    = (const float*)d_in[2];
    const float* b1    = (const float*)d_in[3];
    const float* beta1 = (const float*)d_in[4];
    const float* W2    = (const float*)d_in[5];
    const float* b2    = (const float*)d_in[6];
    const float* beta2 = (const float*)d_in[7];
    const float* W3    = (const float*)d_in[8];
    const float* b3    = (const float*)d_in[9];
    float* out = (float*)d_out;

    // Chunk T so cur1 staging fits in d_ws (plus 512 KB mem-state area).
    const size_t state_bytes = (size_t)BB * 2 * HH * sizeof(float);
    const size_t per_t = (size_t)BB * HH * sizeof(float);   // 256 KB per t
    size_t avail = ws_size > state_bytes ? ws_size - state_bytes : 0;
    int Tc_max = (int)(avail / per_t);
    if (Tc_max > TT) Tc_max = TT;
    Tc_max = (Tc_max / TB) * TB;
    if (Tc_max < TB) Tc_max = TB;   // assume ws >= ~9 MB

    float* cur1 = (float*)d_ws;
    float* state = (float*)((char*)d_ws + (size_t)Tc_max * per_t);

    int t0 = 0;
    while (t0 < TT) {
        int Tc = (TT - t0 < Tc_max) ? (TT - t0) : Tc_max;
        gemm_cur1<<<dim3(Tc / TB, BB), 128, 0, stream>>>(X, W1, b1, cur1, t0, Tc);
        scan_lif<<<BB, 64, 0, stream>>>(cur1,
                                        (t0 == 0) ? hid : (const float*)state, state,
                                        beta1, W2, b2, beta2, W3, b3, out, t0, Tc);
        t0 += Tc;
    }
}